// Round 6
// baseline (2060.182 us; speedup 1.0000x reference)
//
#include <hip/hip_runtime.h>

#define TSTEPS 512
#define DK 512       // D == H == 512
#define NC 2048      // 4H
#define TB 8         // t-slices per GEMM block

typedef unsigned int u32;
typedef unsigned short u16;
typedef _Float16 f16x8 __attribute__((ext_vector_type(8)));
typedef __attribute__((ext_vector_type(4))) float f32x4;
typedef __attribute__((ext_vector_type(4))) unsigned int u32x4;
typedef __attribute__((ext_vector_type(2))) unsigned int u32x2;

static __device__ __forceinline__ u16 f2h(float f) {
    _Float16 h = (_Float16)f;
    u16 u; __builtin_memcpy(&u, &h, 2); return u;
}
static __device__ __forceinline__ float h2f(u16 u) {
    _Float16 h; __builtin_memcpy(&h, &u, 2); return (float)h;
}
static __device__ __forceinline__ u16 f2bf(float f) {
    u32 u = __float_as_uint(f);
    u += 0x7fffu + ((u >> 16) & 1u);
    return (u16)(u >> 16);
}
static __device__ __forceinline__ float sigmoidf_(float x) { return 1.0f / (1.0f + __expf(-x)); }
static __device__ __forceinline__ float tanhf_(float x)    { return 1.0f - 2.0f / (__expf(2.0f * x) + 1.0f); }

// MFMA A/B fragment address (u16 units) for element (k, n) of a 16xK (or Kx16)
// operand: K0=k>>5 block of 1024 B; lane L = n | (((k>>3)&3)<<4); sub j = k&7.
static __device__ __forceinline__ int fragaddr(int k, int n) {
    return ((k >> 5) << 9) + ((n | (((k >> 3) & 3) << 4)) << 3) + (k & 7);
}

// ---- system-scope (MALL coherence point) bypass ops: no fence needed -------
static __device__ __forceinline__ void st_u16_sys(u16* p, u16 v) {
    asm volatile("global_store_short %0, %1, off sc0 sc1"
                 :: "v"(p), "v"((u32)v) : "memory");
}
static __device__ __forceinline__ u32 ld_u32_sys(const u32* p) {
    u32 v;
    asm volatile("global_load_dword %0, %1, off sc0 sc1\n\t"
                 "s_waitcnt vmcnt(0)"
                 : "=v"(v) : "v"(p) : "memory");
    return v;
}

// ---------------------------------------------------------------------------
// K1 (v11): f16 MFMA GEMM for xwt, TB=8 t-slices per block (Wx B-fragments
// preloaded once, reused 8x). Identical math to the round-5 passing kernel.
// xwt[(t*NC + c)*64 + b] = f16( sum_k x[b][t][k]*Wx[k][c] + bias[c] )
// ---------------------------------------------------------------------------
__global__ __launch_bounds__(256)
void gemm_xwt_f16(const float* __restrict__ x, const float* __restrict__ Wx,
                  const float* __restrict__ bias, u16* __restrict__ xwt) {
    __shared__ __align__(16) u16 xF[8192];      // f16 frag order, 16 KB
    const int tid  = threadIdx.x;
    const int lane = tid & 63;
    const int wv   = __builtin_amdgcn_readfirstlane(tid >> 6);  // wave = 16-col group
    const int bid  = (int)blockIdx.x;
    const int tt   = bid >> 5;          // t-group (TB slices)
    const int cb   = bid & 31;
    const int c0   = cb << 6;           // block cols [c0, c0+64)

    // ---- B-fragment preload: Bf[K0][jj] = f16(Wx[k][c0 + wv*16 + (lane&15)])
    f16x8 Bf[16];
    const int coln = c0 + wv * 16 + (lane & 15);
    {
        #pragma unroll
        for (int K0 = 0; K0 < 16; ++K0) {
            f16x8 bv;
            #pragma unroll
            for (int jj = 0; jj < 8; ++jj) {
                const int k = K0 * 32 + ((lane >> 4) << 3) + jj;
                bv[jj] = (_Float16)Wx[(size_t)k * NC + coln];
            }
            Bf[K0] = bv;
        }
    }
    const float bi = bias[coln];

    const int n  = tid >> 4;            // b-row within tile (0..15)
    const int q0 = (tid & 15) << 2;     // k-quad base (0,4,..,60)

    for (int ts = 0; ts < TB; ++ts) {
        const int t = tt * TB + ts;
        for (int bt = 0; bt < 4; ++bt) {
            const float* xp = x + ((size_t)(bt * 16 + n) * TSTEPS + t) * DK;
            __syncthreads();            // protect previous iteration's reads
            #pragma unroll
            for (int kq = 0; kq < 8; ++kq) {
                const int k = q0 + kq * 64;
                const float4 xv = *(const float4*)(xp + k);
                const u16 h0_ = f2h(xv.x), h1_ = f2h(xv.y);
                const u16 h2_ = f2h(xv.z), h3_ = f2h(xv.w);
                const int fa = fragaddr(k, n);
                u32x2 ph;
                ph[0] = (u32)h0_ | ((u32)h1_ << 16);
                ph[1] = (u32)h2_ | ((u32)h3_ << 16);
                *(u32x2*)&xF[fa] = ph;
            }
            __syncthreads();

            f32x4 acc = {0.f, 0.f, 0.f, 0.f};
            #pragma unroll
            for (int K0 = 0; K0 < 16; ++K0) {
                const f16x8 av = *(const f16x8*)&xF[K0 * 512 + lane * 8];
                acc = __builtin_amdgcn_mfma_f32_16x16x32_f16(av, Bf[K0], acc, 0, 0, 0);
            }

            // D: col = lane&15 (c-local), row = (lane>>4)*4 + r (b-local).
            const u16 s0 = f2h(acc[0] + bi);
            const u16 s1 = f2h(acc[1] + bi);
            const u16 s2 = f2h(acc[2] + bi);
            const u16 s3 = f2h(acc[3] + bi);
            u32x2 sv;
            sv[0] = (u32)s0 | ((u32)s1 << 16);
            sv[1] = (u32)s2 | ((u32)s3 << 16);
            const size_t row = (size_t)t * NC + coln;
            *(u32x2*)(xwt + row * 64 + bt * 16 + ((lane >> 4) << 2)) = sv;
        }
    }
}

// ---------------------------------------------------------------------------
// Fallbacks (ws too small): round-1 kernels, [b][t][c] layout.
// ---------------------------------------------------------------------------
__global__ __launch_bounds__(256)
void gemm_xw(const float* __restrict__ x, const float* __restrict__ Wx,
             const float* __restrict__ bias, u16* __restrict__ xw_out) {
    __shared__ float As[16][68];
    __shared__ float Bs[16][64];
    const int tid  = threadIdx.x;
    const int tx   = tid & 15;
    const int ty   = tid >> 4;
    const int row0 = blockIdx.x * 64;
    const int col0 = blockIdx.y * 64;
    const int ar = tid >> 2;
    const int ak = (tid & 3) << 2;
    const int bk = tid >> 4;
    const int bc = (tid & 15) << 2;
    float acc[4][4] = {};
    for (int k0 = 0; k0 < DK; k0 += 16) {
        const float4 av = *(const float4*)(x  + (size_t)(row0 + ar) * DK + k0 + ak);
        const float4 bv = *(const float4*)(Wx + (size_t)(k0 + bk) * NC + col0 + bc);
        __syncthreads();
        As[ak + 0][ar] = av.x; As[ak + 1][ar] = av.y;
        As[ak + 2][ar] = av.z; As[ak + 3][ar] = av.w;
        *(float4*)&Bs[bk][bc] = bv;
        __syncthreads();
        #pragma unroll
        for (int k = 0; k < 16; ++k) {
            float a4[4], b4[4];
            *(float4*)a4 = *(const float4*)&As[k][ty << 2];
            *(float4*)b4 = *(const float4*)&Bs[k][tx << 2];
            #pragma unroll
            for (int i = 0; i < 4; ++i)
                #pragma unroll
                for (int j = 0; j < 4; ++j)
                    acc[i][j] += a4[i] * b4[j];
        }
    }
    #pragma unroll
    for (int i = 0; i < 4; ++i) {
        const size_t row = (size_t)row0 + (ty << 2) + i;
        const int    col = col0 + (tx << 2);
        ushort4 s;
        s.x = f2bf(acc[i][0] + bias[col + 0]);
        s.y = f2bf(acc[i][1] + bias[col + 1]);
        s.z = f2bf(acc[i][2] + bias[col + 2]);
        s.w = f2bf(acc[i][3] + bias[col + 3]);
        *(ushort4*)(xw_out + row * NC + col) = s;
    }
}

static __device__ __forceinline__ float bf2f(u16 u) {
    return __uint_as_float(((u32)u) << 16);
}

__global__ __launch_bounds__(512)
void lstm_rec_old(const u16* __restrict__ xw, const float* __restrict__ Wh,
                  const float* __restrict__ h0, float* __restrict__ out) {
    __shared__ float h_s[DK];
    __shared__ float c_s[DK];
    __shared__ float a_s[NC];
    const int b   = blockIdx.x;
    const int tid = threadIdx.x;
    const int q   = tid << 2;
    h_s[tid] = h0[(size_t)b * DK + tid];
    c_s[tid] = 0.0f;
    __syncthreads();
    for (int t = 0; t < TSTEPS; ++t) {
        const size_t rowoff = ((size_t)b * TSTEPS + t) * NC;
        const ushort4 xv = *(const ushort4*)(xw + rowoff + q);
        float4 acc;
        acc.x = bf2f(xv.x); acc.y = bf2f(xv.y); acc.z = bf2f(xv.z); acc.w = bf2f(xv.w);
        const float* wp = Wh + q;
        #pragma unroll 4
        for (int k = 0; k < DK; k += 4) {
            const float4 hk = *(const float4*)&h_s[k];
            const float4 w0 = *(const float4*)(wp + (size_t)(k + 0) * NC);
            const float4 w1 = *(const float4*)(wp + (size_t)(k + 1) * NC);
            const float4 w2 = *(const float4*)(wp + (size_t)(k + 2) * NC);
            const float4 w3 = *(const float4*)(wp + (size_t)(k + 3) * NC);
            acc.x += hk.x * w0.x + hk.y * w1.x + hk.z * w2.x + hk.w * w3.x;
            acc.y += hk.x * w0.y + hk.y * w1.y + hk.z * w2.y + hk.w * w3.y;
            acc.z += hk.x * w0.z + hk.y * w1.z + hk.z * w2.z + hk.w * w3.z;
            acc.w += hk.x * w0.w + hk.y * w1.w + hk.z * w2.w + hk.w * w3.w;
        }
        *(float4*)&a_s[q] = acc;
        __syncthreads();
        const float ig = sigmoidf_(a_s[tid]);
        const float fg = sigmoidf_(a_s[DK + tid]);
        const float og = sigmoidf_(a_s[2 * DK + tid]);
        const float gg = tanhf_(a_s[3 * DK + tid]);
        const float c  = fg * c_s[tid] + ig * gg;
        const float h  = og * tanhf_(c);
        c_s[tid] = c;
        h_s[tid] = h;
        out[((size_t)b * TSTEPS + t) * DK + tid] = h;
        __syncthreads();
    }
}

// ---------------------------------------------------------------------------
__global__ void init_flg(u32* flg) {
    const int i = threadIdx.x;
    if (i < 256) flg[i] = 0u;    // 4 groups x 64 u32 words (128 u16 flags each)
}

// ---------------------------------------------------------------------------
// K2 (v11): v10's verified fence-free bypass protocol with three latency trims.
// 128 WGs x 256 thr = 4 batch-groups (i, 16 b) x 32 unit-groups (j, 16 u).
// (1) PER-WAVE flags: each wave drains its OWN publish stores (s_waitcnt
//     vmcnt(0)) then lane0 stores a u16 flag -- the WG barrier + tid0
//     serialization leave the critical path. Consumers poll 128 flags as
//     64 u32 words (both u16 halves >= target). Same store->drain->flag
//     ordering the round-2/4/5 kernels verified, per-wave granularity.
// (2) Gate-interleaved B columns: wave wv covers units 4wv..4wv+3 x all 4
//     gates (col = q*512 + 16j + 4wv + p; lane&15 = p*4+q). The i/f/o/g
//     exchange becomes an in-register 4x4 quad transpose (shfl_xor 1,2) --
//     Cx LDS + one barrier deleted.
// (3) Output gather via second quad transpose (shfl_xor 4,8) -> direct
//     float4 out store -- hT + another barrier deleted. 2 barriers/step.
// ---------------------------------------------------------------------------
__global__ __launch_bounds__(256, 1)
void lstm_rec11(const u16* __restrict__ xwt, const float* __restrict__ Wh,
                const float* __restrict__ h0, float* __restrict__ out,
                u16* __restrict__ hG, u16* flg16) {
    __shared__ __align__(16) u16 hF[8192];      // staged h, frag order, 16 KB
    __shared__ int deadS;

    const int tid  = threadIdx.x;
    const int lane = tid & 63;
    const int wv   = __builtin_amdgcn_readfirstlane(tid >> 6);
    const int g    = blockIdx.x;
    const int j    = g & 31;               // unit-group
    const int i    = g >> 5;               // batch-group
    const int p    = (lane >> 2) & 3;      // unit-sub within wave
    const int q    = lane & 3;             // gate index (pre-transpose)
    const int rg   = lane >> 4;            // batch-quad
    const int u    = 16 * j + 4 * wv + p;  // this thread's unit
    const int bp   = 4 * rg + q;           // this thread's local batch
    const int b    = 16 * i + bp;          // global batch

    if (tid == 0) deadS = 0;

    // ---- h0 publish into hG buf 0, plane i (frag order, f16, bypass),
    //      then per-wave drain + wave flag = 1
    {
        const float h0v = h0[(size_t)b * DK + u];
        u16* dst = hG + ((size_t)0 * 4 + i) * 8192;
        st_u16_sys(dst + fragaddr(u, bp), f2h(h0v));
        asm volatile("s_waitcnt vmcnt(0)" ::: "memory");
        if (lane == 0) st_u16_sys(flg16 + (i << 7) + (j << 2) + wv, (u16)1);
    }
    float creg = 0.0f;

    // ---- B-fragment preload: Bf[K0][jj] = f16(Wh[k][q*512 + 16j + 4wv + p])
    f16x8 Bf[16];
    {
        const int coln = q * 512 + 16 * j + 4 * wv + p;
        #pragma unroll
        for (int K0 = 0; K0 < 16; ++K0) {
            f16x8 bv;
            #pragma unroll
            for (int jj = 0; jj < 8; ++jj) {
                const int k = K0 * 32 + ((lane >> 4) << 3) + jj;
                bv[jj] = (_Float16)Wh[(size_t)k * NC + coln];
            }
            Bf[K0] = bv;
        }
    }

    const u32* fp = (const u32*)flg16 + (i << 6) + lane;  // 64 words = 128 flags

    for (int t = 0; t < TSTEPS; ++t) {
        // xw prefetch (in flight during the poll)
        const u16* xp = xwt + (size_t)t * (NC * 64);
        const u16 x0 = xp[(size_t)(0 * 512 + u) * 64 + b];
        const u16 x1 = xp[(size_t)(1 * 512 + u) * 64 + b];
        const u16 x2 = xp[(size_t)(2 * 512 + u) * 64 + b];
        const u16 x3 = xp[(size_t)(3 * 512 + u) * 64 + b];

        // ---- wait for group-i h(t): poll 128 per-wave flags (64 u32 words)
        {
            const u32 target = (u32)(t + 1);
            int spins = 0;
            while (true) {
                const u32 v = ld_u32_sys(fp);
                const int ok = ((v & 0xffffu) >= target) && ((v >> 16) >= target);
                if (__all(ok)) break;
                if (++spins > (1 << 18)) { if (lane == 0) deadS = 1; break; }
                __builtin_amdgcn_s_sleep(1);
            }
        }

        // ---- stage 16 KB (f16 plane) via bypass dwordx4 -> LDS
        {
            const char* srcb = (const char*)(hG + ((size_t)(t & 1) * 4 + i) * 8192);
            const char* p0 = srcb + (size_t)tid * 16;
            u32x4 q0, q1, q2, q3;
            asm volatile("global_load_dwordx4 %0, %1, off sc0 sc1" : "=v"(q0) : "v"(p0));
            asm volatile("global_load_dwordx4 %0, %1, off sc0 sc1" : "=v"(q1) : "v"(p0 + 4096));
            asm volatile("global_load_dwordx4 %0, %1, off sc0 sc1" : "=v"(q2) : "v"(p0 + 8192));
            asm volatile("global_load_dwordx4 %0, %1, off sc0 sc1" : "=v"(q3) : "v"(p0 + 12288));
            asm volatile("s_waitcnt vmcnt(0)" ::: "memory");
            __builtin_amdgcn_sched_barrier(0);
            u32* d32 = (u32*)&hF[0];
            *(u32x4*)(d32 + 0 * 1024 + tid * 4) = q0;
            *(u32x4*)(d32 + 1 * 1024 + tid * 4) = q1;
            *(u32x4*)(d32 + 2 * 1024 + tid * 4) = q2;
            *(u32x4*)(d32 + 3 * 1024 + tid * 4) = q3;
        }
        __syncthreads();           // B1: stage visible to all waves
        if (deadS) break;          // uniform after barrier; loud-fail, no hang

        // ---- MFMA over K=512, two independent chains
        f32x4 acc0 = {0.f, 0.f, 0.f, 0.f};
        f32x4 acc1 = {0.f, 0.f, 0.f, 0.f};
        #pragma unroll
        for (int K0 = 0; K0 < 16; K0 += 2) {
            const f16x8 a0 = *(const f16x8*)&hF[(K0 + 0) * 512 + lane * 8];
            const f16x8 a1 = *(const f16x8*)&hF[(K0 + 1) * 512 + lane * 8];
            acc0 = __builtin_amdgcn_mfma_f32_16x16x32_f16(a0, Bf[K0 + 0], acc0, 0, 0, 0);
            acc1 = __builtin_amdgcn_mfma_f32_16x16x32_f16(a1, Bf[K0 + 1], acc1, 0, 0, 0);
        }
        const f32x4 a = acc0 + acc1;   // a[r] = gate(col p*4+q) at batch-sub 4rg+r

        // ---- 4x4 gate transpose within quad (lanes q=0..3): cv[g] = gate g at r=q
        f32x4 tsw, bv, ssw, cv;
        tsw[0] = __shfl_xor(a[0], 1); tsw[1] = __shfl_xor(a[1], 1);
        tsw[2] = __shfl_xor(a[2], 1); tsw[3] = __shfl_xor(a[3], 1);
        bv[0] = (q & 1) ? tsw[1] : a[0];
        bv[1] = (q & 1) ? a[1]   : tsw[0];
        bv[2] = (q & 1) ? tsw[3] : a[2];
        bv[3] = (q & 1) ? a[3]   : tsw[2];
        ssw[0] = __shfl_xor(bv[0], 2); ssw[1] = __shfl_xor(bv[1], 2);
        ssw[2] = __shfl_xor(bv[2], 2); ssw[3] = __shfl_xor(bv[3], 2);
        cv[0] = (q & 2) ? ssw[2] : bv[0];
        cv[1] = (q & 2) ? ssw[3] : bv[1];
        cv[2] = (q & 2) ? bv[2]  : ssw[0];
        cv[3] = (q & 2) ? bv[3]  : ssw[1];

        // ---- gates for (u, b)
        const float ig = sigmoidf_(cv[0] + h2f(x0));
        const float fg = sigmoidf_(cv[1] + h2f(x1));
        const float og = sigmoidf_(cv[2] + h2f(x2));
        const float gg = tanhf_   (cv[3] + h2f(x3));
        creg = fg * creg + ig * gg;
        const float hnew = og * tanhf_(creg);

        // ---- publish h(t+1) (frag order, f16, bypass), per-wave drain + flag
        {
            u16* dst = hG + ((size_t)((t + 1) & 1) * 4 + i) * 8192;
            st_u16_sys(dst + fragaddr(u, bp), f2h(hnew));
            asm volatile("s_waitcnt vmcnt(0)" ::: "memory");
            if (lane == 0)
                st_u16_sys(flg16 + (i << 7) + (j << 2) + wv, (u16)(t + 2));
        }

        // ---- out gather: quad transpose over p (xor 4, 8) -> float4 store
        {
            const float g4 = __shfl_xor(hnew, 4);
            const float e0 = (p & 1) ? g4 : hnew;
            const float e1 = (p & 1) ? hnew : g4;
            const float f0 = __shfl_xor(e0, 8);
            const float f1 = __shfl_xor(e1, 8);
            float4 o4;
            o4.x = (p & 2) ? f0 : e0;
            o4.y = (p & 2) ? f1 : e1;
            o4.z = (p & 2) ? e0 : f0;
            o4.w = (p & 2) ? e1 : f1;
            if (p == 0)
                *(float4*)(out + ((size_t)b * TSTEPS + t) * DK + 16 * j + 4 * wv) = o4;
        }
        __syncthreads();           // B2: MFMA reads done before next stage-write
    }
}

// ---------------------------------------------------------------------------
extern "C" void kernel_launch(void* const* d_in, const int* in_sizes, int n_in,
                              void* d_out, int out_size, void* d_ws, size_t ws_size,
                              hipStream_t stream) {
    const float* x    = (const float*)d_in[0];
    const float* h0   = (const float*)d_in[1];
    const float* Wx   = (const float*)d_in[2];
    const float* Wh   = (const float*)d_in[3];
    const float* bias = (const float*)d_in[4];
    float* out = (float*)d_out;

    u16* xw = (u16*)d_ws;
    const size_t XW_BYTES = (size_t)TSTEPS * NC * 64 * sizeof(u16);   // 134217728
    u16* hG  = (u16*)((char*)d_ws + XW_BYTES);                        // 128 KB used of 256 KB
    // flags live in the unused upper half of the hG region (hG uses 131072 B)
    u16* flg = (u16*)((char*)d_ws + XW_BYTES + 200704);               // 1 KB: 4 x 128 u16
    const size_t need = XW_BYTES + 262144 + 512;

    if (ws_size >= need) {
        gemm_xwt_f16<<<(TSTEPS / TB) * 32, 256, 0, stream>>>(x, Wx, bias, xw);
        init_flg<<<1, 256, 0, stream>>>((u32*)flg);
        lstm_rec11<<<128, 256, 0, stream>>>(xw, Wh, h0, out, hG, flg);
    } else {
        dim3 g1(512, 32);
        gemm_xw<<<g1, 256, 0, stream>>>(x, Wx, bias, xw);
        lstm_rec_old<<<64, 512, 0, stream>>>(xw, Wh, h0, out);
    }
}

// Round 7
// 1423.103 us; speedup vs baseline: 1.4477x; 1.4477x over previous
//
#include <hip/hip_runtime.h>

#define TSTEPS 512
#define DK 512       // D == H == 512
#define NC 2048      // 4H
#define TB 4         // t-slices per GEMM block

typedef unsigned int u32;
typedef unsigned short u16;
typedef _Float16 f16x8 __attribute__((ext_vector_type(8)));
typedef __attribute__((ext_vector_type(4))) float f32x4;
typedef __attribute__((ext_vector_type(4))) unsigned int u32x4;
typedef __attribute__((ext_vector_type(2))) unsigned int u32x2;

static __device__ __forceinline__ u16 f2h(float f) {
    _Float16 h = (_Float16)f;
    u16 u; __builtin_memcpy(&u, &h, 2); return u;
}
static __device__ __forceinline__ float h2f(u16 u) {
    _Float16 h; __builtin_memcpy(&h, &u, 2); return (float)h;
}
static __device__ __forceinline__ u16 f2bf(float f) {
    u32 u = __float_as_uint(f);
    u += 0x7fffu + ((u >> 16) & 1u);
    return (u16)(u >> 16);
}
static __device__ __forceinline__ float sigmoidf_(float x) { return 1.0f / (1.0f + __expf(-x)); }
static __device__ __forceinline__ float tanhf_(float x)    { return 1.0f - 2.0f / (__expf(2.0f * x) + 1.0f); }

// MFMA A/B fragment address (u16 units) for element (k, n) of a 16xK (or Kx16)
// operand: K0=k>>5 block of 1024 B; lane L = n | (((k>>3)&3)<<4); sub j = k&7.
static __device__ __forceinline__ int fragaddr(int k, int n) {
    return ((k >> 5) << 9) + ((n | (((k >> 3) & 3) << 4)) << 3) + (k & 7);
}

// ---- system-scope (MALL coherence point) bypass ops: no fence needed -------
static __device__ __forceinline__ void st_u16_sys(u16* p, u16 v) {
    asm volatile("global_store_short %0, %1, off sc0 sc1"
                 :: "v"(p), "v"((u32)v) : "memory");
}
static __device__ __forceinline__ void st_u32_sys(u32* p, u32 v) {
    asm volatile("global_store_dword %0, %1, off sc0 sc1"
                 :: "v"(p), "v"(v) : "memory");
}
static __device__ __forceinline__ u32 ld_u32_sys(const u32* p) {
    u32 v;
    asm volatile("global_load_dword %0, %1, off sc0 sc1\n\t"
                 "s_waitcnt vmcnt(0)"
                 : "=v"(v) : "v"(p) : "memory");
    return v;
}

// ---------------------------------------------------------------------------
// K0 (v12): one-time Wx f32 [k][c] -> f16 transposed [c][k] (2 MB in ws).
// 64x64 LDS tile transpose; same f32->f16 rounding as the verified GEMM cast,
// so downstream xwt is bit-identical.
// ---------------------------------------------------------------------------
__global__ __launch_bounds__(256)
void wx_to_f16t(const float* __restrict__ Wx, u16* __restrict__ Wxt) {
    __shared__ float tile[64][65];
    const int kb = blockIdx.x & 7;    // 512/64 k-tiles
    const int cb = blockIdx.x >> 3;   // 2048/64 c-tiles
    const int k0 = kb << 6, c0 = cb << 6;
    const int tr  = threadIdx.x >> 2;        // 0..63 (k row)
    const int tc4 = (threadIdx.x & 3) << 4;  // 0,16,32,48 (c base)
    #pragma unroll
    for (int c = 0; c < 16; c += 4) {
        const float4 v = *(const float4*)(Wx + (size_t)(k0 + tr) * NC + c0 + tc4 + c);
        tile[tr][tc4 + c + 0] = v.x;
        tile[tr][tc4 + c + 1] = v.y;
        tile[tr][tc4 + c + 2] = v.z;
        tile[tr][tc4 + c + 3] = v.w;
    }
    __syncthreads();
    const int cc  = threadIdx.x >> 2;        // 0..63 (c row of output)
    const int kk0 = (threadIdx.x & 3) << 4;  // 0,16,32,48 (k base)
    u32 pk[8];
    #pragma unroll
    for (int m = 0; m < 8; ++m) {
        const u16 a = f2h(tile[kk0 + 2 * m + 0][cc]);
        const u16 b = f2h(tile[kk0 + 2 * m + 1][cc]);
        pk[m] = (u32)a | ((u32)b << 16);
    }
    u16* dst = Wxt + (size_t)(c0 + cc) * DK + k0 + kk0;
    *(u32x4*)dst = *(u32x4*)&pk[0];
    *(u32x4*)(dst + 8) = *(u32x4*)&pk[4];
}

// ---------------------------------------------------------------------------
// K1 (v12): f16 MFMA GEMM for xwt, B-fragments from pre-transposed f16 Wxt
// (16 vector loads/lane instead of 128 scalar f32 loads). Math identical to
// the round-5 verified kernel -> xwt bit-identical.
// xwt[(t*NC + c)*64 + b] = f16( sum_k x[b][t][k]*Wx[k][c] + bias[c] )
// ---------------------------------------------------------------------------
__global__ __launch_bounds__(256)
void gemm_xwt_f16t(const float* __restrict__ x, const u16* __restrict__ Wxt,
                   const float* __restrict__ bias, u16* __restrict__ xwt) {
    __shared__ __align__(16) u16 xF[8192];      // f16 frag order, 16 KB
    const int tid  = threadIdx.x;
    const int lane = tid & 63;
    const int wv   = __builtin_amdgcn_readfirstlane(tid >> 6);  // wave = 16-col group
    const int bid  = (int)blockIdx.x;
    const int tt   = bid >> 5;          // t-group (TB slices)
    const int cb   = bid & 31;
    const int c0   = cb << 6;           // block cols [c0, c0+64)

    // ---- B-fragment preload: vector loads from Wxt[c][k]
    f16x8 Bf[16];
    const int coln = c0 + wv * 16 + (lane & 15);
    {
        const u16* wp = Wxt + (size_t)coln * DK + ((lane >> 4) << 3);
        #pragma unroll
        for (int K0 = 0; K0 < 16; ++K0)
            Bf[K0] = *(const f16x8*)(wp + K0 * 32);
    }
    const float bi = bias[coln];

    const int n  = tid >> 4;            // b-row within tile (0..15)
    const int q0 = (tid & 15) << 2;     // k-quad base (0,4,..,60)

    for (int ts = 0; ts < TB; ++ts) {
        const int t = tt * TB + ts;
        for (int bt = 0; bt < 4; ++bt) {
            const float* xp = x + ((size_t)(bt * 16 + n) * TSTEPS + t) * DK;
            __syncthreads();            // protect previous iteration's reads
            #pragma unroll
            for (int kq = 0; kq < 8; ++kq) {
                const int k = q0 + kq * 64;
                const float4 xv = *(const float4*)(xp + k);
                const u16 h0_ = f2h(xv.x), h1_ = f2h(xv.y);
                const u16 h2_ = f2h(xv.z), h3_ = f2h(xv.w);
                const int fa = fragaddr(k, n);
                u32x2 ph;
                ph[0] = (u32)h0_ | ((u32)h1_ << 16);
                ph[1] = (u32)h2_ | ((u32)h3_ << 16);
                *(u32x2*)&xF[fa] = ph;
            }
            __syncthreads();

            f32x4 acc = {0.f, 0.f, 0.f, 0.f};
            #pragma unroll
            for (int K0 = 0; K0 < 16; ++K0) {
                const f16x8 av = *(const f16x8*)&xF[K0 * 512 + lane * 8];
                acc = __builtin_amdgcn_mfma_f32_16x16x32_f16(av, Bf[K0], acc, 0, 0, 0);
            }

            // D: col = lane&15 (c-local), row = (lane>>4)*4 + r (b-local).
            const u16 s0 = f2h(acc[0] + bi);
            const u16 s1 = f2h(acc[1] + bi);
            const u16 s2 = f2h(acc[2] + bi);
            const u16 s3 = f2h(acc[3] + bi);
            u32x2 sv;
            sv[0] = (u32)s0 | ((u32)s1 << 16);
            sv[1] = (u32)s2 | ((u32)s3 << 16);
            const size_t row = (size_t)t * NC + coln;
            *(u32x2*)(xwt + row * 64 + bt * 16 + ((lane >> 4) << 2)) = sv;
        }
    }
}

// ---------------------------------------------------------------------------
// K1-alt (verified round 5): f16 MFMA GEMM reading Wx f32 directly (used when
// ws has no room for Wxt).
// ---------------------------------------------------------------------------
__global__ __launch_bounds__(256)
void gemm_xwt_f16(const float* __restrict__ x, const float* __restrict__ Wx,
                  const float* __restrict__ bias, u16* __restrict__ xwt) {
    __shared__ __align__(16) u16 xF[8192];      // f16 frag order, 16 KB
    const int tid  = threadIdx.x;
    const int lane = tid & 63;
    const int wv   = __builtin_amdgcn_readfirstlane(tid >> 6);
    const int bid  = (int)blockIdx.x;
    const int tt   = bid >> 5;
    const int cb   = bid & 31;
    const int c0   = cb << 6;

    f16x8 Bf[16];
    const int coln = c0 + wv * 16 + (lane & 15);
    {
        #pragma unroll
        for (int K0 = 0; K0 < 16; ++K0) {
            f16x8 bv;
            #pragma unroll
            for (int jj = 0; jj < 8; ++jj) {
                const int k = K0 * 32 + ((lane >> 4) << 3) + jj;
                bv[jj] = (_Float16)Wx[(size_t)k * NC + coln];
            }
            Bf[K0] = bv;
        }
    }
    const float bi = bias[coln];

    const int n  = tid >> 4;
    const int q0 = (tid & 15) << 2;

    for (int ts = 0; ts < TB; ++ts) {
        const int t = tt * TB + ts;
        for (int bt = 0; bt < 4; ++bt) {
            const float* xp = x + ((size_t)(bt * 16 + n) * TSTEPS + t) * DK;
            __syncthreads();
            #pragma unroll
            for (int kq = 0; kq < 8; ++kq) {
                const int k = q0 + kq * 64;
                const float4 xv = *(const float4*)(xp + k);
                const u16 h0_ = f2h(xv.x), h1_ = f2h(xv.y);
                const u16 h2_ = f2h(xv.z), h3_ = f2h(xv.w);
                const int fa = fragaddr(k, n);
                u32x2 ph;
                ph[0] = (u32)h0_ | ((u32)h1_ << 16);
                ph[1] = (u32)h2_ | ((u32)h3_ << 16);
                *(u32x2*)&xF[fa] = ph;
            }
            __syncthreads();

            f32x4 acc = {0.f, 0.f, 0.f, 0.f};
            #pragma unroll
            for (int K0 = 0; K0 < 16; ++K0) {
                const f16x8 av = *(const f16x8*)&xF[K0 * 512 + lane * 8];
                acc = __builtin_amdgcn_mfma_f32_16x16x32_f16(av, Bf[K0], acc, 0, 0, 0);
            }

            const u16 s0 = f2h(acc[0] + bi);
            const u16 s1 = f2h(acc[1] + bi);
            const u16 s2 = f2h(acc[2] + bi);
            const u16 s3 = f2h(acc[3] + bi);
            u32x2 sv;
            sv[0] = (u32)s0 | ((u32)s1 << 16);
            sv[1] = (u32)s2 | ((u32)s3 << 16);
            const size_t row = (size_t)t * NC + coln;
            *(u32x2*)(xwt + row * 64 + bt * 16 + ((lane >> 4) << 2)) = sv;
        }
    }
}

// ---------------------------------------------------------------------------
// Fallbacks (ws too small): round-1 kernels, [b][t][c] layout.
// ---------------------------------------------------------------------------
__global__ __launch_bounds__(256)
void gemm_xw(const float* __restrict__ x, const float* __restrict__ Wx,
             const float* __restrict__ bias, u16* __restrict__ xw_out) {
    __shared__ float As[16][68];
    __shared__ float Bs[16][64];
    const int tid  = threadIdx.x;
    const int tx   = tid & 15;
    const int ty   = tid >> 4;
    const int row0 = blockIdx.x * 64;
    const int col0 = blockIdx.y * 64;
    const int ar = tid >> 2;
    const int ak = (tid & 3) << 2;
    const int bk = tid >> 4;
    const int bc = (tid & 15) << 2;
    float acc[4][4] = {};
    for (int k0 = 0; k0 < DK; k0 += 16) {
        const float4 av = *(const float4*)(x  + (size_t)(row0 + ar) * DK + k0 + ak);
        const float4 bv = *(const float4*)(Wx + (size_t)(k0 + bk) * NC + col0 + bc);
        __syncthreads();
        As[ak + 0][ar] = av.x; As[ak + 1][ar] = av.y;
        As[ak + 2][ar] = av.z; As[ak + 3][ar] = av.w;
        *(float4*)&Bs[bk][bc] = bv;
        __syncthreads();
        #pragma unroll
        for (int k = 0; k < 16; ++k) {
            float a4[4], b4[4];
            *(float4*)a4 = *(const float4*)&As[k][ty << 2];
            *(float4*)b4 = *(const float4*)&Bs[k][tx << 2];
            #pragma unroll
            for (int i = 0; i < 4; ++i)
                #pragma unroll
                for (int j = 0; j < 4; ++j)
                    acc[i][j] += a4[i] * b4[j];
        }
    }
    #pragma unroll
    for (int i = 0; i < 4; ++i) {
        const size_t row = (size_t)row0 + (ty << 2) + i;
        const int    col = col0 + (tx << 2);
        ushort4 s;
        s.x = f2bf(acc[i][0] + bias[col + 0]);
        s.y = f2bf(acc[i][1] + bias[col + 1]);
        s.z = f2bf(acc[i][2] + bias[col + 2]);
        s.w = f2bf(acc[i][3] + bias[col + 3]);
        *(ushort4*)(xw_out + row * NC + col) = s;
    }
}

static __device__ __forceinline__ float bf2f(u16 u) {
    return __uint_as_float(((u32)u) << 16);
}

__global__ __launch_bounds__(512)
void lstm_rec_old(const u16* __restrict__ xw, const float* __restrict__ Wh,
                  const float* __restrict__ h0, float* __restrict__ out) {
    __shared__ float h_s[DK];
    __shared__ float c_s[DK];
    __shared__ float a_s[NC];
    const int b   = blockIdx.x;
    const int tid = threadIdx.x;
    const int q   = tid << 2;
    h_s[tid] = h0[(size_t)b * DK + tid];
    c_s[tid] = 0.0f;
    __syncthreads();
    for (int t = 0; t < TSTEPS; ++t) {
        const size_t rowoff = ((size_t)b * TSTEPS + t) * NC;
        const ushort4 xv = *(const ushort4*)(xw + rowoff + q);
        float4 acc;
        acc.x = bf2f(xv.x); acc.y = bf2f(xv.y); acc.z = bf2f(xv.z); acc.w = bf2f(xv.w);
        const float* wp = Wh + q;
        #pragma unroll 4
        for (int k = 0; k < DK; k += 4) {
            const float4 hk = *(const float4*)&h_s[k];
            const float4 w0 = *(const float4*)(wp + (size_t)(k + 0) * NC);
            const float4 w1 = *(const float4*)(wp + (size_t)(k + 1) * NC);
            const float4 w2 = *(const float4*)(wp + (size_t)(k + 2) * NC);
            const float4 w3 = *(const float4*)(wp + (size_t)(k + 3) * NC);
            acc.x += hk.x * w0.x + hk.y * w1.x + hk.z * w2.x + hk.w * w3.x;
            acc.y += hk.x * w0.y + hk.y * w1.y + hk.z * w2.y + hk.w * w3.y;
            acc.z += hk.x * w0.z + hk.y * w1.z + hk.z * w2.z + hk.w * w3.z;
            acc.w += hk.x * w0.w + hk.y * w1.w + hk.z * w2.w + hk.w * w3.w;
        }
        *(float4*)&a_s[q] = acc;
        __syncthreads();
        const float ig = sigmoidf_(a_s[tid]);
        const float fg = sigmoidf_(a_s[DK + tid]);
        const float og = sigmoidf_(a_s[2 * DK + tid]);
        const float gg = tanhf_(a_s[3 * DK + tid]);
        const float c  = fg * c_s[tid] + ig * gg;
        const float h  = og * tanhf_(c);
        c_s[tid] = c;
        h_s[tid] = h;
        out[((size_t)b * TSTEPS + t) * DK + tid] = h;
        __syncthreads();
    }
}

// ---------------------------------------------------------------------------
__global__ void init_flg(u32* flg) {
    const int i = threadIdx.x;
    if (i < 128) flg[i] = 0u;
}

// ---------------------------------------------------------------------------
// K2 (v10, verified round 5 — BYTE-IDENTICAL revert): fence-free bypass
// protocol, f16 single-plane h. 128 WGs x 256 thr = 4 batch-groups x 32
// unit-groups. Per step: poll 32 flags -> stage 16 KB h -> 16 f16 MFMA ->
// Cx transpose -> gates -> publish f16 -> __syncthreads drain -> tid0 flag
// -> wv0 out store (overlaps next step's poll in waves 1-3).
// ---------------------------------------------------------------------------
__global__ __launch_bounds__(256, 1)
void lstm_rec10(const u16* __restrict__ xwt, const float* __restrict__ Wh,
                const float* __restrict__ h0, float* __restrict__ out,
                u16* __restrict__ hG, u32* flg) {
    __shared__ __align__(16) u16 hF[8192];      // staged h, frag order, 16 KB
    __shared__ float Cx[4][16][17];             // [gate][unit][b'] pad  4.25 KB
    __shared__ float hT[256];                   // [unit][b']            1 KB
    __shared__ int deadS;

    const int tid  = threadIdx.x;
    const int lane = tid & 63;
    const int wv   = __builtin_amdgcn_readfirstlane(tid >> 6);  // wave = gate
    const int g    = blockIdx.x;
    const int j    = g & 31;       // unit-group
    const int i    = g >> 5;       // batch-group
    const int du   = tid >> 4;     // gate-phase: local unit 0..15
    const int bp   = tid & 15;     // gate-phase: local batch 0..15
    const int u    = 16 * j + du;  // global unit
    const int b    = 16 * i + bp;  // global batch

    if (tid == 0) deadS = 0;

    // ---- h0 publish into hG buf 0, plane i (frag order, f16, bypass)
    {
        const float h0v = h0[(size_t)b * DK + u];
        u16* dst = hG + ((size_t)0 * 4 + i) * 8192;
        st_u16_sys(dst + fragaddr(u, bp), f2h(h0v));
    }
    float creg = 0.0f;
    __syncthreads();   // drains all waves' vmcnt: h0 at coherence point
    if (tid == 0) st_u32_sys(&flg[(i << 5) + j], 1u);

    // ---- B-fragment preload to VGPRs: Bf[K0][jj] = f16(Wh[k][wv*512+16j+(lane&15)])
    f16x8 Bf[16];
    {
        const int coln = 16 * j + (lane & 15);
        #pragma unroll
        for (int K0 = 0; K0 < 16; ++K0) {
            f16x8 bv;
            #pragma unroll
            for (int jj = 0; jj < 8; ++jj) {
                const int k = K0 * 32 + ((lane >> 4) << 3) + jj;
                bv[jj] = (_Float16)Wh[(size_t)k * NC + wv * 512 + coln];
            }
            Bf[K0] = bv;
        }
    }

    const u32* fp = &flg[(i << 5) + (lane & 31)];  // group's 128B flag region

    for (int t = 0; t < TSTEPS; ++t) {
        // xw prefetch (coalesced 32B runs), in flight during the poll
        const u16* xp = xwt + (size_t)t * (NC * 64);
        const u16 x0 = xp[(0 * 512 + u) * 64 + b];
        const u16 x1 = xp[(1 * 512 + u) * 64 + b];
        const u16 x2 = xp[(2 * 512 + u) * 64 + b];
        const u16 x3 = xp[(3 * 512 + u) * 64 + b];

        // ---- wait for group-i h(t): bypass polls of the group's flag words
        {
            const u32 target = (u32)(t + 1);
            int spins = 0;
            while (true) {
                const u32 v = ld_u32_sys(fp);
                if (__all((int)(v >= target))) break;
                if (++spins > (1 << 18)) { if (lane == 0) deadS = 1; break; }
                __builtin_amdgcn_s_sleep(1);
            }
        }

        // ---- stage 16 KB (f16 plane) via bypass dwordx4 -> LDS
        {
            const char* srcb = (const char*)(hG + ((size_t)(t & 1) * 4 + i) * 8192);
            const char* p0 = srcb + (size_t)tid * 16;
            u32x4 q0, q1, q2, q3;
            asm volatile("global_load_dwordx4 %0, %1, off sc0 sc1" : "=v"(q0) : "v"(p0));
            asm volatile("global_load_dwordx4 %0, %1, off sc0 sc1" : "=v"(q1) : "v"(p0 + 4096));
            asm volatile("global_load_dwordx4 %0, %1, off sc0 sc1" : "=v"(q2) : "v"(p0 + 8192));
            asm volatile("global_load_dwordx4 %0, %1, off sc0 sc1" : "=v"(q3) : "v"(p0 + 12288));
            asm volatile("s_waitcnt vmcnt(0)" ::: "memory");
            __builtin_amdgcn_sched_barrier(0);
            u32* d32 = (u32*)&hF[0];
            *(u32x4*)(d32 + 0 * 1024 + tid * 4) = q0;
            *(u32x4*)(d32 + 1 * 1024 + tid * 4) = q1;
            *(u32x4*)(d32 + 2 * 1024 + tid * 4) = q2;
            *(u32x4*)(d32 + 3 * 1024 + tid * 4) = q3;
        }
        __syncthreads();
        if (deadS) break;          // uniform after barrier; loud-fail, no hang

        // ---- MFMA: acc[16b x 16cols] over K=512, f16 single chain
        f32x4 acc = {0.f, 0.f, 0.f, 0.f};
        #pragma unroll
        for (int K0 = 0; K0 < 16; ++K0) {
            const f16x8 ah = *(const f16x8*)&hF[K0 * 512 + lane * 8];
            acc = __builtin_amdgcn_mfma_f32_16x16x32_f16(ah, Bf[K0], acc, 0, 0, 0);
        }

        // C layout: col=lane&15 (unit), row=(lane>>4)*4+r (b'). -> Cx[gate][unit][b']
        #pragma unroll
        for (int r = 0; r < 4; ++r)
            Cx[wv][lane & 15][((lane >> 4) << 2) + r] = acc[r];
        __syncthreads();

        // ---- gate phase: thread (du, bp)
        const float ai = Cx[0][du][bp] + h2f(x0);
        const float af = Cx[1][du][bp] + h2f(x1);
        const float ao = Cx[2][du][bp] + h2f(x2);
        const float ag = Cx[3][du][bp] + h2f(x3);
        const float ig = sigmoidf_(ai);
        const float fg = sigmoidf_(af);
        const float og = sigmoidf_(ao);
        const float gg = tanhf_(ag);
        creg = fg * creg + ig * gg;
        const float hnew = og * tanhf_(creg);

        // publish h(t+1) (frag order, f16, bypass write-through)
        {
            u16* dst = hG + ((size_t)((t + 1) & 1) * 4 + i) * 8192;
            st_u16_sys(dst + fragaddr(u, bp), f2h(hnew));
        }
        hT[tid] = hnew;   // hT[du*16+bp]
        __syncthreads();  // publish stores drained in every wave + hT visible

        if (tid == 0) st_u32_sys(&flg[(i << 5) + j], (u32)(t + 2));

        if (wv == 0) {    // out[b][t][16j+qd*4 .. +4]
            const int bq = lane >> 2;
            const int qd = lane & 3;
            float4 o4;
            o4.x = hT[(qd * 4 + 0) * 16 + bq];
            o4.y = hT[(qd * 4 + 1) * 16 + bq];
            o4.z = hT[(qd * 4 + 2) * 16 + bq];
            o4.w = hT[(qd * 4 + 3) * 16 + bq];
            *(float4*)(out + ((size_t)(16 * i + bq) * TSTEPS + t) * DK + 16 * j + qd * 4) = o4;
        }
    }
}

// ---------------------------------------------------------------------------
extern "C" void kernel_launch(void* const* d_in, const int* in_sizes, int n_in,
                              void* d_out, int out_size, void* d_ws, size_t ws_size,
                              hipStream_t stream) {
    const float* x    = (const float*)d_in[0];
    const float* h0   = (const float*)d_in[1];
    const float* Wx   = (const float*)d_in[2];
    const float* Wh   = (const float*)d_in[3];
    const float* bias = (const float*)d_in[4];
    float* out = (float*)d_out;

    u16* xw = (u16*)d_ws;
    const size_t XW_BYTES = (size_t)TSTEPS * NC * 64 * sizeof(u16);   // 134217728
    u16* hG  = (u16*)((char*)d_ws + XW_BYTES);                        // 128 KB used of 256 KB
    u32* flg = (u32*)((char*)d_ws + XW_BYTES + 262144);               // 4x32 u32
    u16* Wxt = (u16*)((char*)d_ws + XW_BYTES + 262144 + 512);         // 2 MB f16 Wx^T
    const size_t need  = XW_BYTES + 262144 + 512;
    const size_t need2 = need + (size_t)NC * DK * sizeof(u16);        // +2 MB

    if (ws_size >= need2) {
        wx_to_f16t<<<256, 256, 0, stream>>>(Wx, Wxt);
        gemm_xwt_f16t<<<(TSTEPS / TB) * 32, 256, 0, stream>>>(x, Wxt, bias, xw);
        init_flg<<<1, 128, 0, stream>>>(flg);
        lstm_rec10<<<128, 256, 0, stream>>>(xw, Wh, h0, out, hG, flg);
    } else if (ws_size >= need) {
        gemm_xwt_f16<<<(TSTEPS / TB) * 32, 256, 0, stream>>>(x, Wx, bias, xw);
        init_flg<<<1, 128, 0, stream>>>(flg);
        lstm_rec10<<<128, 256, 0, stream>>>(xw, Wh, h0, out, hG, flg);
    } else {
        dim3 g1(512, 32);
        gemm_xw<<<g1, 256, 0, stream>>>(x, Wx, bias, xw);
        lstm_rec_old<<<64, 512, 0, stream>>>(xw, Wh, h0, out);
    }
}